// Round 1
// 492.775 us; speedup vs baseline: 1.0784x; 1.0784x over previous
//
#include <hip/hip_runtime.h>
#include <cstdint>
#include <cstddef>

// Problem constants: B=64, T=2048, M=512, P=512

typedef float  floatx4 __attribute__((ext_vector_type(4)));
typedef short  shortx8 __attribute__((ext_vector_type(8)));

__device__ __forceinline__ short f2bf_rne(float f) {
  unsigned u = __float_as_uint(f);
  unsigned r = u + 0x7FFFu + ((u >> 16) & 1u);
  return (short)(r >> 16);
}

// pack two fp32 -> two bf16 (truncation) in one v_perm_b32
__device__ __forceinline__ unsigned pack_bf_trunc(float lo, float hi) {
  return __builtin_amdgcn_perm(__float_as_uint(hi), __float_as_uint(lo), 0x07060302u);
}

#define GLOAD_LDS16(gptr, lptr)                                                 \
  __builtin_amdgcn_global_load_lds(                                             \
      (const __attribute__((address_space(1))) void*)(gptr),                    \
      (__attribute__((address_space(3))) void*)(lptr), 16, 0, 0)

#define SB() __builtin_amdgcn_sched_barrier(0)
#define WAIT_VM(n) asm volatile("s_waitcnt vmcnt(" #n ")" ::: "memory")
#define WAIT_LGKM0() asm volatile("s_waitcnt lgkmcnt(0)" ::: "memory")

// ---------------------------------------------------------------------------
// Kernel 1: prep.
//   blocks 0..127:   S[b][n] = ds@W_d + b_wd + b_ud  (fp32)
//   blocks 128..383: UT = pre-swizzled bf16 LDS byte-image of U_d^T:
//                    image[cb][kt] is the 16 KB LDS tile [n 0..255][k 0..31]
//                    with 16B-slot XOR swizzle slot' = slot ^ (n&3), so the
//                    GEMM can stage it with linear global_load_lds.
//   blocks 384..511: zero d_out (logit accumulator)
// ---------------------------------------------------------------------------
extern "C" __global__ __launch_bounds__(256) void prep_kernel(
    const float* __restrict__ hidden, const float* __restrict__ cell,
    const float* __restrict__ W_d, const float* __restrict__ b_wd,
    const float* __restrict__ U_d, const float* __restrict__ b_ud,
    float* __restrict__ S, short* __restrict__ UT, float* __restrict__ lzero)
{
  int bx = blockIdx.x, tid = threadIdx.x;
  if (bx < 128) {
    int idx = bx * 256 + tid;          // 0..32767
    int b = idx >> 9, n = idx & 511;
    const float* h = hidden + b * 512;
    const float* c = cell   + b * 512;
    float acc = b_wd[n] + b_ud[n];
    for (int k = 0; k < 512; ++k) acc = fmaf(h[k], W_d[k * 512 + n], acc);
    for (int k = 0; k < 512; ++k) acc = fmaf(c[k], W_d[(k + 512) * 512 + n], acc);
    S[idx] = acc;
  } else if (bx < 384) {
    int idx = (bx - 128) * 1024 + tid * 4;   // short index into UT image
    int cbp = idx >> 17;                     // 0..1   (column block)
    int r2  = idx & 131071;
    int ktp = r2 >> 13;                      // 0..15  (K tile of 32)
    int sI  = r2 & 8191;                     // short within 16 KB tile image
    int n    = sI >> 5;                      // 0..255 (row: 64 B = 32 bf16)
    int slot = (sI >> 3) & 3;                // physical 16B slot in row
    int b16  = sI & 7;                       // 0 or 4 (tid*4 alignment)
    int kb16 = slot ^ (n & 3);               // logical 16B slot (inverse swz)
    int k0 = ktp * 32 + (kb16 << 3) + b16;   // first of 4 consecutive k
    int ng = cbp * 256 + n;
    unsigned lo = (unsigned short)f2bf_rne(U_d[(size_t)(k0 + 0) * 512 + ng]) |
                  ((unsigned)(unsigned short)f2bf_rne(U_d[(size_t)(k0 + 1) * 512 + ng]) << 16);
    unsigned hi = (unsigned short)f2bf_rne(U_d[(size_t)(k0 + 2) * 512 + ng]) |
                  ((unsigned)(unsigned short)f2bf_rne(U_d[(size_t)(k0 + 3) * 512 + ng]) << 16);
    uint2 w; w.x = lo; w.y = hi;
    *(uint2*)(UT + idx) = w;
  } else {
    int idx = ((bx - 384) * 256 + tid) * 4;
    floatx4 z = {0.f, 0.f, 0.f, 0.f};
    *(floatx4*)(lzero + idx) = z;
  }
}

// ---------------------------------------------------------------------------
// Kernel 2: fused GEMM + tanh + dot(v) -> atomicAdd partial logits.
// 256x256 tile / block, 8 waves (2x4 of 128x64), mfma 16x16x32 bf16, BK=32.
// A: fp32 global -> regs -> bf16 pack -> swizzled LDS (ds_write_b64).
// B: pre-swizzled global image -> linear global_load_lds.
// Double-buffered LDS, 1 barrier per K-tile, counted vmcnt (A(t+2) prefetch
// stays in flight across the barrier), setprio around MFMA clusters.
// ---------------------------------------------------------------------------
extern "C" __global__ __launch_bounds__(512, 2) void attn_gemm(
    const float* __restrict__ A, const short* __restrict__ UT,
    const float* __restrict__ S, const float* __restrict__ vd,
    float* __restrict__ lout)
{
  __shared__ short As[2][8192];   // [buf][256 rows][32 k] bf16, swizzled; 16 KB each
  __shared__ short Bs[2][8192];   // [buf][256 n   ][32 k] bf16, swizzled; 16 KB each

  const int tid = threadIdx.x;
  const int bx  = blockIdx.x;
  // XCD-aware swizzle: 1024 blocks, 128 per XCD; the 2 col-blocks of a
  // row-block are consecutive on one XCD (share the A panel in L2).
  const int xcd = bx & 7;
  const int wg  = xcd * 128 + (bx >> 3);
  const int cb  = wg & 1;            // 0..1
  const int rb  = wg >> 1;           // 0..511
  const int row0 = rb << 8;
  const int col0 = cb << 8;
  const int wave = tid >> 6;
  const int lane = tid & 63;
  const int wr = wave >> 2, wc = wave & 3;   // 2 x 4 wave grid
  const int q = lane >> 4, l15 = lane & 15;

  // --- A staging: 4 x float4 loads / thread / K-tile (rows of 128 B) ---
  const float* asrc[4];
  int awr[4];
#pragma unroll
  for (int j = 0; j < 4; ++j) {
    int row = j * 64 + (tid >> 3);
    int ch  = tid & 7;                 // 16B chunk within row (k = ch*4..ch*4+3)
    asrc[j] = A + (size_t)(row0 + row) * 512 + ch * 4;
    awr[j]  = row * 32 + ((((ch >> 1) ^ (row & 3)) << 3) + (ch & 1) * 4);
  }
  // --- B staging: 2 x global_load_lds / thread / K-tile ---
  const short* bsrc[2];
  int bdst[2];
#pragma unroll
  for (int j = 0; j < 2; ++j) {
    int ws = j * 8 + wave;             // 16 wave-shots of 1 KB
    bsrc[j] = UT + cb * 131072 + ws * 512 + lane * 8;
    bdst[j] = ws * 512;                // wave-uniform LDS short offset
  }

  // --- iteration-invariant fragment LDS offsets (swizzled) ---
  int aoff[8], boff[4];
#pragma unroll
  for (int tr = 0; tr < 8; ++tr) {
    int row = wr * 128 + tr * 16 + l15;
    aoff[tr] = row * 32 + ((q ^ (row & 3)) << 3);
  }
#pragma unroll
  for (int tc = 0; tc < 4; ++tc) {
    int n = wc * 64 + tc * 16 + l15;
    boff[tc] = n * 32 + ((q ^ (n & 3)) << 3);
  }

  floatx4 acc[8][4];
#pragma unroll
  for (int i = 0; i < 8; ++i)
#pragma unroll
    for (int j = 0; j < 4; ++j)
      acc[i][j] = (floatx4){0.f, 0.f, 0.f, 0.f};

  floatx4 areg[4];

  // ------------------- prologue -------------------
#pragma unroll
  for (int j = 0; j < 4; ++j) areg[j] = *(const floatx4*)(asrc[j]);   // A(0)
  SB();
#pragma unroll
  for (int j = 0; j < 2; ++j) GLOAD_LDS16(bsrc[j], &Bs[0][bdst[j]]);  // B(0)
  SB();
  WAIT_VM(2); SB();                    // A(0) landed (B(0) may remain)
#pragma unroll
  for (int j = 0; j < 4; ++j) {
    uint2 w;
    w.x = pack_bf_trunc(areg[j].x, areg[j].y);
    w.y = pack_bf_trunc(areg[j].z, areg[j].w);
    *(uint2*)(&As[0][0] + awr[j]) = w;
  }
  SB();
#pragma unroll
  for (int j = 0; j < 4; ++j) areg[j] = *(const floatx4*)(asrc[j] + 32);  // A(1)
  SB();
  WAIT_VM(4); SB();                    // B(0) done, A(1) still in flight
  WAIT_LGKM0(); SB();
  __builtin_amdgcn_s_barrier(); SB();

  // ------------------- main loop: 16 K-tiles of 32 -------------------
#pragma unroll
  for (int t = 0; t < 16; ++t) {
    const int cur = t & 1;
    const short* Ab = &As[cur][0];
    const short* Bb = &Bs[cur][0];
    shortx8 af[4], bfr[4];
    // P1: B frags (all 4, persist) + A frags tr 0..3, then 16 MFMA
#pragma unroll
    for (int tc = 0; tc < 4; ++tc) bfr[tc] = *(const shortx8*)(Bb + boff[tc]);
#pragma unroll
    for (int tr = 0; tr < 4; ++tr) af[tr] = *(const shortx8*)(Ab + aoff[tr]);
    WAIT_LGKM0(); SB();
    __builtin_amdgcn_s_setprio(1);
#pragma unroll
    for (int tr = 0; tr < 4; ++tr)
#pragma unroll
      for (int tc = 0; tc < 4; ++tc)
        acc[tr][tc] = __builtin_amdgcn_mfma_f32_16x16x32_bf16(
            af[tr], bfr[tc], acc[tr][tc], 0, 0, 0);
    __builtin_amdgcn_s_setprio(0);
    SB();
    // P2: staging cluster for tile t+1 / prefetch t+2
    if (t < 15) {
      WAIT_VM(0); SB();                // A(t+1) regs ready (only thing in flight)
      short* An = &As[cur ^ 1][0];
#pragma unroll
      for (int j = 0; j < 4; ++j) {
        uint2 w;
        w.x = pack_bf_trunc(areg[j].x, areg[j].y);
        w.y = pack_bf_trunc(areg[j].z, areg[j].w);
        *(uint2*)(An + awr[j]) = w;
      }
#pragma unroll
      for (int j = 0; j < 2; ++j)
        GLOAD_LDS16(bsrc[j] + (t + 1) * 8192, &Bs[cur ^ 1][bdst[j]]);
      SB();                            // keep glds older than the A prefetch
      if (t < 14) {
#pragma unroll
        for (int j = 0; j < 4; ++j)
          areg[j] = *(const floatx4*)(asrc[j] + (t + 2) * 32);
      }
      SB();
    }
    // P3: A frags tr 4..7, 16 MFMA
#pragma unroll
    for (int tr = 0; tr < 4; ++tr) af[tr] = *(const shortx8*)(Ab + aoff[tr + 4]);
    WAIT_LGKM0(); SB();                // also drains our ds_writes
    __builtin_amdgcn_s_setprio(1);
#pragma unroll
    for (int tr = 0; tr < 4; ++tr)
#pragma unroll
      for (int tc = 0; tc < 4; ++tc)
        acc[tr + 4][tc] = __builtin_amdgcn_mfma_f32_16x16x32_bf16(
            af[tr], bfr[tc], acc[tr + 4][tc], 0, 0, 0);
    __builtin_amdgcn_s_setprio(0);
    SB();
    if (t < 15) {
      if (t < 14) { WAIT_VM(4); }      // B(t+1) done; A(t+2) stays in flight
      else        { WAIT_VM(0); }      // t=14: no A(16) outstanding
      SB();
      __builtin_amdgcn_s_barrier();
      SB();
    }
  }

  // ------------- epilogue: e = tanh(acc + S[b][n]); dot with v; atomics -------------
  const int bb = rb >> 3;              // 256 rows per block, 2048 rows per batch
  const float* Srow = S + bb * 512;
  float sv[4], vv[4];
#pragma unroll
  for (int tc = 0; tc < 4; ++tc) {
    int n = col0 + wc * 64 + tc * 16 + l15;
    sv[tc] = Srow[n];
    vv[tc] = vd[n];
  }
#pragma unroll
  for (int tr = 0; tr < 8; ++tr) {
#pragma unroll
    for (int r = 0; r < 4; ++r) {
      float ssum = 0.f;
#pragma unroll
      for (int tc = 0; tc < 4; ++tc) {
        float x = acc[tr][tc][r] + sv[tc];
        x = fminf(15.f, fmaxf(-15.f, x));
        float e2 = __expf(2.f * x);
        float e = (e2 - 1.f) / (e2 + 1.f);  // tanh
        ssum += e * vv[tc];
      }
      ssum += __shfl_xor(ssum, 1);
      ssum += __shfl_xor(ssum, 2);
      ssum += __shfl_xor(ssum, 4);
      ssum += __shfl_xor(ssum, 8);
      if (l15 == 0) {
        int row = row0 + wr * 128 + tr * 16 + q * 4 + r;
        atomicAdd(lout + row, ssum);
      }
    }
  }
}

// ---------------------------------------------------------------------------
// Kernel 3: softmax over T=2048, in place on d_out. One block per batch.
// ---------------------------------------------------------------------------
extern "C" __global__ __launch_bounds__(256) void softmax_t(float* __restrict__ l)
{
  int b = blockIdx.x, tid = threadIdx.x;
  int wave = tid >> 6, lane = tid & 63;
  float* row = l + (size_t)b * 2048;
  float v[8];
  float mx = -3.4e38f;
#pragma unroll
  for (int i = 0; i < 8; ++i) { v[i] = row[tid + i * 256]; mx = fmaxf(mx, v[i]); }
#pragma unroll
  for (int m = 1; m < 64; m <<= 1) mx = fmaxf(mx, __shfl_xor(mx, m));
  __shared__ float red[8];
  if (lane == 0) red[wave] = mx;
  __syncthreads();
  mx = fmaxf(fmaxf(red[0], red[1]), fmaxf(red[2], red[3]));
  float s = 0.f;
#pragma unroll
  for (int i = 0; i < 8; ++i) { v[i] = __expf(v[i] - mx); s += v[i]; }
#pragma unroll
  for (int m = 1; m < 64; m <<= 1) s += __shfl_xor(s, m);
  if (lane == 0) red[4 + wave] = s;
  __syncthreads();
  s = red[4] + red[5] + red[6] + red[7];
  float inv = 1.f / s;
#pragma unroll
  for (int i = 0; i < 8; ++i) row[tid + i * 256] = v[i] * inv;
}

// ---------------------------------------------------------------------------
extern "C" void kernel_launch(void* const* d_in, const int* in_sizes, int n_in,
                              void* d_out, int out_size, void* d_ws, size_t ws_size,
                              hipStream_t stream) {
  const float* hidden = (const float*)d_in[0];
  const float* cell   = (const float*)d_in[1];
  const float* enc    = (const float*)d_in[2];
  const float* W_d    = (const float*)d_in[3];
  const float* b_wd   = (const float*)d_in[4];
  const float* U_d    = (const float*)d_in[5];
  const float* b_ud   = (const float*)d_in[6];
  const float* v_d    = (const float*)d_in[7];
  // d_in[8] = b_vd: constant shift over T -> softmax-invariant, unused.
  float* out = (float*)d_out;                     // logits then softmax, in place
  float* S   = (float*)d_ws;                      // 64*512 fp32   = 128 KB
  short* UT  = (short*)((char*)d_ws + 32768 * sizeof(float));  // 512 KB image

  hipLaunchKernelGGL(prep_kernel, dim3(512), dim3(256), 0, stream,
                     hidden, cell, W_d, b_wd, U_d, b_ud, S, UT, out);
  hipLaunchKernelGGL(attn_gemm, dim3(1024), dim3(512), 0, stream,
                     enc, UT, S, v_d, out);
  hipLaunchKernelGGL(softmax_t, dim3(64), dim3(256), 0, stream, out);
}